// Round 3
// baseline (2311.939 us; speedup 1.0000x reference)
//
#include <hip/hip_runtime.h>
#include <stdint.h>

#define B_ 4
#define S_ 2048
#define D_ 1024
#define H_ 16
#define A_ 64
#define LN_EPS 1e-3f
#define L2E 1.4426950408889634f

typedef __bf16 bf16x8 __attribute__((ext_vector_type(8)));
typedef float f32x4 __attribute__((ext_vector_type(4)));

__device__ __forceinline__ f32x4 mfma16(bf16x8 a, bf16x8 b, f32x4 c) {
    return __builtin_amdgcn_mfma_f32_16x16x32_bf16(a, b, c, 0, 0, 0);
}

// async global->LDS, 16B per lane (wave-uniform LDS base + lane*16)
__device__ __forceinline__ void glds16(const void* g, void* l) {
    __builtin_amdgcn_global_load_lds(
        (const __attribute__((address_space(1))) void*)g,
        (__attribute__((address_space(3))) void*)l, 16, 0, 0);
}

// stage a [128 rows][32 k] bf16 tile: 8 chunks of 16 rows (1KB each), 2 per wave
__device__ __forceinline__ void glds_tile128(const __bf16* __restrict__ src, size_t ld,
                                             __bf16* lds, int w, int lane) {
    int r = lane >> 2;
    int c = (lane & 3) * 8;
    #pragma unroll
    for (int i = 0; i < 2; ++i) {
        int r0 = (w + i * 4) * 16;
        glds16(src + (size_t)(r0 + r) * ld + c, lds + r0 * 32);
    }
}

// fragment loads from linear [128][32] LDS + MFMA block
template <int NI, int NJ>
__device__ __forceinline__ void mfma_tileL(const __bf16* As, const __bf16* Bs,
                                           int wm, int wn, int fr, int fg,
                                           f32x4 (&acc)[NI][NJ]) {
    bf16x8 af[NI], bv[NJ];
    #pragma unroll
    for (int i = 0; i < NI; ++i)
        af[i] = *(const bf16x8*)(As + (wm + i * 16 + fr) * 32 + fg * 8);
    #pragma unroll
    for (int j = 0; j < NJ; ++j)
        bv[j] = *(const bf16x8*)(Bs + (wn + j * 16 + fr) * 32 + fg * 8);
    #pragma unroll
    for (int i = 0; i < NI; ++i)
        #pragma unroll
        for (int j = 0; j < NJ; ++j)
            acc[i][j] = mfma16(af[i], bv[j], acc[i][j]);
}

// ---------------- tiled transpose + f32->bf16 convert ----------------
__global__ void k_tr_cvt(const float* __restrict__ in, __bf16* __restrict__ out,
                         int R, int C) {
    __shared__ float tile[32][33];
    size_t gbase = (size_t)blockIdx.z * R * C;
    int r0 = blockIdx.y * 32, c0 = blockIdx.x * 32;
    #pragma unroll
    for (int i = threadIdx.y; i < 32; i += 8)
        tile[i][threadIdx.x] = in[gbase + (size_t)(r0 + i) * C + c0 + threadIdx.x];
    __syncthreads();
    #pragma unroll
    for (int i = threadIdx.y; i < 32; i += 8)
        out[gbase + (size_t)(c0 + i) * R + r0 + threadIdx.x] = (__bf16)tile[threadIdx.x][i];
}

// ---------------- elementwise f32 -> bf16 ----------------
__global__ void k_cvt(const float* __restrict__ in, __bf16* __restrict__ out, int n8) {
    int i = blockIdx.x * blockDim.x + threadIdx.x;
    if (i >= n8) return;
    const float4* p = (const float4*)(in + (size_t)i * 8);
    float4 f0 = p[0], f1 = p[1];
    __bf16 v[8] = {(__bf16)f0.x, (__bf16)f0.y, (__bf16)f0.z, (__bf16)f0.w,
                   (__bf16)f1.x, (__bf16)f1.y, (__bf16)f1.z, (__bf16)f1.w};
    *(uint4*)(out + (size_t)i * 8) = *(const uint4*)v;
}

// ---------------- Q/K projection, 2-phase dbuf ----------------
__global__ __launch_bounds__(256) void k_proj_gemm(
    const __bf16* __restrict__ Ab, const __bf16* __restrict__ Bt,
    const float* __restrict__ bias, float scale, __bf16* __restrict__ out) {
    __shared__ __bf16 As[2][128 * 32];
    __shared__ __bf16 Bs[2][128 * 32];
    int m0 = blockIdx.y * 128, n0 = blockIdx.x * 128;
    int t = threadIdx.x, lane = t & 63, w = t >> 6;
    int wm = (w >> 1) * 64, wn = (w & 1) * 64;
    int fr = lane & 15, fg = lane >> 4;
    const __bf16* Abase = Ab + (size_t)m0 * D_;
    const __bf16* Bbase = Bt + (size_t)n0 * D_;
    f32x4 acc[4][4] = {};
    glds_tile128(Abase, D_, As[0], w, lane);
    glds_tile128(Bbase, D_, Bs[0], w, lane);
    __syncthreads();
    int cur = 0;
    const int nt = D_ / 32;
    for (int tt = 0; tt < nt; ++tt) {
        if (tt + 1 < nt) {
            glds_tile128(Abase + (tt + 1) * 32, D_, As[cur ^ 1], w, lane);
            glds_tile128(Bbase + (tt + 1) * 32, D_, Bs[cur ^ 1], w, lane);
        }
        mfma_tileL<4, 4>(As[cur], Bs[cur], wm, wn, fr, fg, acc);
        __syncthreads();
        cur ^= 1;
    }
    #pragma unroll
    for (int j = 0; j < 4; ++j) {
        int n = n0 + wn + j * 16 + fr;
        float bv = bias[n];
        #pragma unroll
        for (int i = 0; i < 4; ++i)
            #pragma unroll
            for (int jj = 0; jj < 4; ++jj) {
                int m = m0 + wm + i * 16 + fg * 4 + jj;
                out[(size_t)m * (H_ * A_) + n] = (__bf16)((acc[i][j][jj] + bv) * scale);
            }
    }
}

// ---------------- scores + exp + row-sum; coalesced P store via LDS ----------------
__global__ __launch_bounds__(256) void k_scores(
    const __bf16* __restrict__ qpb, const __bf16* __restrict__ kpb,
    __bf16* __restrict__ P, float* __restrict__ invl, int hg0) {
    __shared__ __bf16 Qs[64 * 72];
    __shared__ __bf16 Ks[64 * 72];
    __shared__ __bf16 Ps[64 * 72];
    int qt = blockIdx.x;
    int hl = blockIdx.y;
    int h = hg0 + hl;
    int s0 = qt * 64;
    int t = threadIdx.x, lane = t & 63, w = t >> 6;
    int fr = lane & 15, fg = lane >> 4;
    __bf16* Pb = P + (size_t)hl * S_ * S_;
    float* ilb = invl + (size_t)hl * S_;
    #pragma unroll
    for (int i = 0; i < 2; ++i) {
        int id = t + i * 256;
        int row = id >> 3, ch = (id & 7) * 8;
        *(uint4*)(Qs + row * 72 + ch) =
            *(const uint4*)(qpb + (size_t)(s0 + row) * (H_ * A_) + h * A_ + ch);
    }
    float lsum[4] = {0.f, 0.f, 0.f, 0.f};
    for (int kt = 0; kt <= qt; ++kt) {
        int t0 = kt * 64;
        __syncthreads();  // prev Ks reads + Ps store done
        #pragma unroll
        for (int i = 0; i < 2; ++i) {
            int id = t + i * 256;
            int row = id >> 3, ch = (id & 7) * 8;
            *(uint4*)(Ks + row * 72 + ch) =
                *(const uint4*)(kpb + (size_t)(t0 + row) * (H_ * A_) + h * A_ + ch);
        }
        __syncthreads();
        f32x4 sacc[4] = {};
        #pragma unroll
        for (int st = 0; st < 2; ++st) {
            bf16x8 aq = *(const bf16x8*)(Qs + (w * 16 + fr) * 72 + st * 32 + fg * 8);
            #pragma unroll
            for (int c = 0; c < 4; ++c) {
                bf16x8 bkf = *(const bf16x8*)(Ks + (c * 16 + fr) * 72 + st * 32 + fg * 8);
                sacc[c] = mfma16(aq, bkf, sacc[c]);
            }
        }
        bool diag = (kt == qt);
        #pragma unroll
        for (int c = 0; c < 4; ++c) {
            int tg = t0 + c * 16 + fr;
            #pragma unroll
            for (int jj = 0; jj < 4; ++jj) {
                int sg = s0 + w * 16 + fg * 4 + jj;
                float p = exp2f(sacc[c][jj] * L2E);
                if (diag && tg > sg) p = 0.f;
                lsum[jj] += p;
                Ps[(w * 16 + fg * 4 + jj) * 72 + c * 16 + fr] = (__bf16)p;
            }
        }
        __syncthreads();  // Ps tile complete
        #pragma unroll
        for (int i = 0; i < 2; ++i) {
            int id = t + i * 256;
            int row = id >> 3, ch = (id & 7) * 8;
            *(uint4*)(Pb + (size_t)(s0 + row) * S_ + t0 + ch) =
                *(const uint4*)(Ps + row * 72 + ch);
        }
    }
    // zero-fill one extra 64-tile past the diagonal for even qt (PV uses 128-row tiles)
    if ((qt & 1) == 0) {
        int t0 = (qt + 1) * 64;
        uint4 z = {0, 0, 0, 0};
        #pragma unroll
        for (int i = 0; i < 2; ++i) {
            int id = t + i * 256;
            int row = id >> 3, ch = (id & 7) * 8;
            *(uint4*)(Pb + (size_t)(s0 + row) * S_ + t0 + ch) = z;
        }
    }
    #pragma unroll
    for (int jj = 0; jj < 4; ++jj) {
        float v = lsum[jj];
        v += __shfl_xor(v, 1);
        v += __shfl_xor(v, 2);
        v += __shfl_xor(v, 4);
        v += __shfl_xor(v, 8);
        if (fr == 0)
            ilb[s0 + w * 16 + fg * 4 + jj] = 1.f / v;
    }
}

// ---------------- P @ V (causal GEMM), 2-phase dbuf, 1/l epilogue ----------------
__global__ __launch_bounds__(256) void k_pv_gemm(
    const __bf16* __restrict__ P, const __bf16* __restrict__ kvtb,
    const float* __restrict__ invl, __bf16* __restrict__ att, int aslot0) {
    __shared__ __bf16 As[2][128 * 32];
    __shared__ __bf16 Bs[2][128 * 32];
    int hl = blockIdx.z;
    int qt = blockIdx.y;
    int n0 = blockIdx.x * 128;
    int m0 = qt * 128;
    int nt = (qt + 1) * 4;
    int t = threadIdx.x, lane = t & 63, w = t >> 6;
    int wm = (w >> 1) * 64, wn = (w & 1) * 64;
    int fr = lane & 15, fg = lane >> 4;
    const __bf16* Ab = P + (size_t)hl * S_ * S_ + (size_t)m0 * S_;
    const __bf16* Bb = kvtb + (size_t)n0 * S_;
    f32x4 acc[4][4] = {};
    glds_tile128(Ab, S_, As[0], w, lane);
    glds_tile128(Bb, S_, Bs[0], w, lane);
    __syncthreads();
    int cur = 0;
    for (int tt = 0; tt < nt; ++tt) {
        if (tt + 1 < nt) {
            glds_tile128(Ab + (tt + 1) * 32, S_, As[cur ^ 1], w, lane);
            glds_tile128(Bb + (tt + 1) * 32, S_, Bs[cur ^ 1], w, lane);
        }
        mfma_tileL<4, 4>(As[cur], Bs[cur], wm, wn, fr, fg, acc);
        __syncthreads();
        cur ^= 1;
    }
    const float* ilb = invl + (size_t)hl * S_;
    float il[4][4];
    #pragma unroll
    for (int i = 0; i < 4; ++i)
        #pragma unroll
        for (int jj = 0; jj < 4; ++jj)
            il[i][jj] = ilb[m0 + wm + i * 16 + fg * 4 + jj];
    __bf16* ob = att + (size_t)(aslot0 + hl) * S_ * D_;
    #pragma unroll
    for (int j = 0; j < 4; ++j) {
        int n = n0 + wn + j * 16 + fr;
        #pragma unroll
        for (int i = 0; i < 4; ++i)
            #pragma unroll
            for (int jj = 0; jj < 4; ++jj) {
                int m = m0 + wm + i * 16 + fg * 4 + jj;
                ob[(size_t)m * D_ + n] = (__bf16)(acc[i][j][jj] * il[i][jj]);
            }
    }
}

// ---------------- per-head Wo GEMM + bias + relu + head-sum (HC heads/block) ----------------
__global__ __launch_bounds__(256) void k_headsum(
    const __bf16* __restrict__ att, const __bf16* __restrict__ Wot,
    const float* __restrict__ bo, float* __restrict__ asum,
    int hb0, int HC, int accum) {
    __shared__ __bf16 As[2][128 * 32];
    __shared__ __bf16 Bs[2][128 * 32];
    int p = blockIdx.z;
    int m0 = blockIdx.y * 128;
    int n0 = blockIdx.x * 128;
    int t = threadIdx.x, lane = t & 63, w = t >> 6;
    int wm = (w >> 1) * 64, wn = (w & 1) * 64;
    int fr = lane & 15, fg = lane >> 4;
    int ntot = HC * 32;
    auto stage = [&](int tt, int buf) {
        int hc = tt >> 5, k0 = (tt & 31) * 32;
        int hlz = p * HC + hc;
        glds_tile128(att + ((size_t)hlz * S_ + m0) * D_ + k0, D_, As[buf], w, lane);
        glds_tile128(Wot + ((size_t)(hb0 + hlz) * D_ + n0) * D_ + k0, D_, Bs[buf], w, lane);
    };
    f32x4 acc[4][4] = {};
    f32x4 sum[4][4] = {};
    stage(0, 0);
    __syncthreads();
    int cur = 0;
    for (int tt = 0; tt < ntot; ++tt) {
        if (tt + 1 < ntot) stage(tt + 1, cur ^ 1);
        mfma_tileL<4, 4>(As[cur], Bs[cur], wm, wn, fr, fg, acc);
        __syncthreads();
        cur ^= 1;
        if ((tt & 31) == 31) {  // head boundary: bias+relu fold, reset acc
            int habs = hb0 + p * HC + (tt >> 5);
            #pragma unroll
            for (int j = 0; j < 4; ++j) {
                int n = n0 + wn + j * 16 + fr;
                float bv = bo[(size_t)habs * D_ + n];
                #pragma unroll
                for (int i = 0; i < 4; ++i)
                    #pragma unroll
                    for (int jj = 0; jj < 4; ++jj) {
                        sum[i][j][jj] += fmaxf(acc[i][j][jj] + bv, 0.f);
                        acc[i][j][jj] = 0.f;
                    }
            }
        }
    }
    float* dst = asum + (size_t)p * S_ * D_;
    #pragma unroll
    for (int j = 0; j < 4; ++j) {
        int n = n0 + wn + j * 16 + fr;
        #pragma unroll
        for (int i = 0; i < 4; ++i)
            #pragma unroll
            for (int jj = 0; jj < 4; ++jj) {
                int m = m0 + wm + i * 16 + fg * 4 + jj;
                if (accum)
                    dst[(size_t)m * D_ + n] += sum[i][j][jj];
                else
                    dst[(size_t)m * D_ + n] = sum[i][j][jj];
            }
    }
}

// ---------------- residual + NP-partial-sum + LayerNorm (per batch) ----------------
__global__ __launch_bounds__(256) void k_ln(
    const float* __restrict__ x1b, const float* __restrict__ parts,
    const float* __restrict__ gamma, const float* __restrict__ beta,
    float* __restrict__ outb, int NP) {
    int row = blockIdx.x;
    size_t base = (size_t)row * D_;
    int c = threadIdx.x * 4;
    float4 a = *(const float4*)(x1b + base + c);
    float x[4] = {a.x, a.y, a.z, a.w};
    for (int p = 0; p < NP; ++p) {
        const float4 v = *(const float4*)(parts + ((size_t)p * S_ + row) * D_ + c);
        x[0] += v.x; x[1] += v.y; x[2] += v.z; x[3] += v.w;
    }
    float sm = x[0] + x[1] + x[2] + x[3];
    float s2 = x[0] * x[0] + x[1] * x[1] + x[2] * x[2] + x[3] * x[3];
    #pragma unroll
    for (int m = 32; m >= 1; m >>= 1) {
        sm += __shfl_xor(sm, m);
        s2 += __shfl_xor(s2, m);
    }
    __shared__ float r1[4], r2[4];
    int w = threadIdx.x >> 6;
    if ((threadIdx.x & 63) == 0) { r1[w] = sm; r2[w] = s2; }
    __syncthreads();
    sm = r1[0] + r1[1] + r1[2] + r1[3];
    s2 = r2[0] + r2[1] + r2[2] + r2[3];
    float mean = sm * (1.f / D_);
    float var = s2 * (1.f / D_) - mean * mean;
    float rstd = rsqrtf(var + LN_EPS);
    #pragma unroll
    for (int jj = 0; jj < 4; ++jj)
        outb[base + c + jj] = gamma[c + jj] * (x[jj] - mean) * rstd + beta[c + jj];
}

// ---------------- host ----------------
extern "C" void kernel_launch(void* const* d_in, const int* in_sizes, int n_in,
                              void* d_out, int out_size, void* d_ws, size_t ws_size,
                              hipStream_t stream) {
    (void)in_sizes; (void)n_in; (void)out_size;
    const float* qin   = (const float*)d_in[0];
    const float* kvin  = (const float*)d_in[1];
    const float* Wq    = (const float*)d_in[2];
    const float* bq    = (const float*)d_in[3];
    const float* Wk    = (const float*)d_in[4];
    const float* bk    = (const float*)d_in[5];
    const float* Wo    = (const float*)d_in[6];
    const float* bo    = (const float*)d_in[7];
    const float* gamma = (const float*)d_in[8];
    const float* beta  = (const float*)d_in[9];
    float* out = (float*)d_out;
    char* ws = (char*)d_ws;

    size_t off = 0;
    auto alloc = [&](size_t bytes) {
        size_t o = off;
        off += (bytes + 255) & ~(size_t)255;
        return o;
    };
    size_t o_wqt = alloc((size_t)H_ * A_ * D_ * 2);
    size_t o_wkt = alloc((size_t)H_ * A_ * D_ * 2);
    size_t o_wot = alloc((size_t)H_ * D_ * D_ * 2);
    size_t o_kvt = alloc((size_t)B_ * D_ * S_ * 2);
    size_t o_qb  = alloc((size_t)B_ * S_ * D_ * 2);
    size_t o_kvb = alloc((size_t)B_ * S_ * D_ * 2);
    size_t o_qp  = alloc((size_t)B_ * S_ * H_ * A_ * 2);
    size_t o_kp  = alloc((size_t)B_ * S_ * H_ * A_ * 2);
    size_t fixed = off;

    // tiers: AG = heads materialized in att per headsum window; HGp = heads per
    // scores/pv dispatch (P slots); NP = headsum z-partials (asum[NP][S][D] f32).
    int AG = 2, HGp = 1, NP = 1;
    {
        bool found = false;
        const int ags[4] = {16, 8, 4, 2};
        const int nps[3] = {4, 2, 1};
        const int hgs[4] = {8, 4, 2, 1};
        for (int ia = 0; ia < 4 && !found; ++ia)
            for (int in_ = 0; in_ < 3 && !found; ++in_)
                for (int ih = 0; ih < 4 && !found; ++ih) {
                    int ag = ags[ia], np = nps[in_], hg = hgs[ih];
                    if (hg > ag || np > ag || (ag % np) || (ag % hg)) continue;
                    size_t need = fixed
                                + (size_t)np * S_ * D_ * 4      // asum partials (per batch)
                                + (size_t)hg * S_ * S_ * 2      // P slots
                                + (size_t)ag * S_ * D_ * 2      // att window
                                + (size_t)hg * S_ * 4           // invl
                                + (1u << 20);
                    if (need <= ws_size) { AG = ag; NP = np; HGp = hg; found = true; }
                }
    }
    size_t o_as  = alloc((size_t)NP * S_ * D_ * 4);
    size_t o_P   = alloc((size_t)HGp * S_ * S_ * 2);
    size_t o_att = alloc((size_t)AG * S_ * D_ * 2);
    size_t o_il  = alloc((size_t)HGp * S_ * 4);

    __bf16* wqt = (__bf16*)(ws + o_wqt);
    __bf16* wkt = (__bf16*)(ws + o_wkt);
    __bf16* wot = (__bf16*)(ws + o_wot);
    __bf16* kvt = (__bf16*)(ws + o_kvt);
    __bf16* qb  = (__bf16*)(ws + o_qb);
    __bf16* kvb = (__bf16*)(ws + o_kvb);
    __bf16* qp  = (__bf16*)(ws + o_qp);
    __bf16* kp  = (__bf16*)(ws + o_kp);
    float*  asum = (float*)(ws + o_as);
    __bf16* Pp  = (__bf16*)(ws + o_P);
    __bf16* att = (__bf16*)(ws + o_att);
    float*  il  = (float*)(ws + o_il);

    // transposed bf16 weights + V^T, and bf16 activations
    k_tr_cvt<<<dim3(A_ / 32, D_ / 32, H_), dim3(32, 8), 0, stream>>>(Wq, wqt, D_, A_);
    k_tr_cvt<<<dim3(A_ / 32, D_ / 32, H_), dim3(32, 8), 0, stream>>>(Wk, wkt, D_, A_);
    k_tr_cvt<<<dim3(D_ / 32, D_ / 32, H_), dim3(32, 8), 0, stream>>>(Wo, wot, D_, D_);
    k_tr_cvt<<<dim3(D_ / 32, S_ / 32, B_), dim3(32, 8), 0, stream>>>(kvin, kvt, S_, D_);
    int n8 = B_ * S_ * D_ / 8;
    k_cvt<<<(n8 + 255) / 256, 256, 0, stream>>>(qin, qb, n8);
    k_cvt<<<(n8 + 255) / 256, 256, 0, stream>>>(kvin, kvb, n8);
    // projections (q pre-scaled by 1/sqrt(A))
    k_proj_gemm<<<dim3(8, 64), 256, 0, stream>>>(qb, wqt, bq, 0.125f, qp);
    k_proj_gemm<<<dim3(8, 64), 256, 0, stream>>>(kvb, wkt, bk, 1.0f, kp);

    int HC = AG / NP;
    for (int b = 0; b < B_; ++b) {
        const __bf16* qpb  = qp + (size_t)b * S_ * (H_ * A_);
        const __bf16* kpb  = kp + (size_t)b * S_ * (H_ * A_);
        const __bf16* kvtb = kvt + (size_t)b * D_ * S_;
        for (int hb0 = 0; hb0 < H_; hb0 += AG) {
            for (int hg0 = hb0; hg0 < hb0 + AG; hg0 += HGp) {
                k_scores<<<dim3(32, HGp), 256, 0, stream>>>(qpb, kpb, Pp, il, hg0);
                k_pv_gemm<<<dim3(D_ / 128, S_ / 128, HGp), 256, 0, stream>>>(
                    Pp, kvtb, il, att, hg0 - hb0);
            }
            k_headsum<<<dim3(D_ / 128, S_ / 128, NP), 256, 0, stream>>>(
                att, wot, bo, asum, hb0, HC, hb0 != 0);
        }
        k_ln<<<S_, 256, 0, stream>>>(qin + (size_t)b * S_ * D_, asum, gamma, beta,
                                     out + (size_t)b * S_ * D_, NP);
    }
}

// Round 4
// 1870.420 us; speedup vs baseline: 1.2361x; 1.2361x over previous
//
#include <hip/hip_runtime.h>
#include <stdint.h>

#define B_ 4
#define S_ 2048
#define D_ 1024
#define H_ 16
#define A_ 64
#define LN_EPS 1e-3f
#define L2E 1.4426950408889634f
#define LDK 40

typedef __bf16 bf16x8 __attribute__((ext_vector_type(8)));
typedef float f32x4 __attribute__((ext_vector_type(4)));

__device__ __forceinline__ f32x4 mfma16(bf16x8 a, bf16x8 b, f32x4 c) {
    return __builtin_amdgcn_mfma_f32_16x16x32_bf16(a, b, c, 0, 0, 0);
}
__device__ __forceinline__ void glds16(const void* g, void* l) {
    __builtin_amdgcn_global_load_lds(
        (const __attribute__((address_space(1))) void*)g,
        (__attribute__((address_space(3))) void*)l, 16, 0, 0);
}

// ---- 8-phase 256x256 GEMM core helpers (BK=64, 8 waves, 128KB LDS) ----
// LDS halves are [128 rows][64 k] bf16, 16KB. XOR swizzle on 16B slots:
#define SWZ(slot, r) ((slot) ^ (((r) & 1) << 2) ^ (((r) >> 1) & 3))

// stage one half-tile: linear LDS dest (glds requirement), swizzle folded
// into the per-lane GLOBAL source column (rule #21: both-sides-or-neither).
__device__ __forceinline__ void stage_half(const __bf16* __restrict__ src, size_t ld,
                                           __bf16* lhalf, int w, int lane) {
    #pragma unroll
    for (int i = 0; i < 2; ++i) {
        int ch = w * 2 + i;                 // 16 chunks of 8 rows
        int r = ch * 8 + (lane >> 3);       // row 0..127 within half
        int sl = SWZ(lane & 7, r);          // source 16B-slot
        glds16(src + (size_t)r * ld + sl * 8, lhalf + ch * 512);
    }
}
__device__ __forceinline__ bf16x8 fragS(const __bf16* h, int r, int ks, int fg) {
    return *(const bf16x8*)(h + r * 64 + SWZ(ks * 4 + fg, r) * 8);
}

// ---------------- tiled transpose + f32->bf16 convert ----------------
__global__ void k_tr_cvt(const float* __restrict__ in, __bf16* __restrict__ out,
                         int R, int C) {
    __shared__ float tile[32][33];
    size_t gbase = (size_t)blockIdx.z * R * C;
    int r0 = blockIdx.y * 32, c0 = blockIdx.x * 32;
    #pragma unroll
    for (int i = threadIdx.y; i < 32; i += 8)
        tile[i][threadIdx.x] = in[gbase + (size_t)(r0 + i) * C + c0 + threadIdx.x];
    __syncthreads();
    #pragma unroll
    for (int i = threadIdx.y; i < 32; i += 8)
        out[gbase + (size_t)(c0 + i) * R + r0 + threadIdx.x] = (__bf16)tile[threadIdx.x][i];
}

// ---------------- proj staging helpers (reg-staged, padded LDS) ----------------
__device__ __forceinline__ void stage128_bf16(__bf16* dst, const __bf16* src, int ld, int t) {
    #pragma unroll
    for (int i = 0; i < 2; ++i) {
        int id = t + i * 256;
        int row = id >> 2, ch = (id & 3) * 8;
        *(uint4*)(dst + row * LDK + ch) = *(const uint4*)(src + (size_t)row * ld + ch);
    }
}
__device__ __forceinline__ void stage128_f32(__bf16* dst, const float* src, int ld, int t) {
    #pragma unroll
    for (int i = 0; i < 2; ++i) {
        int id = t + i * 256;
        int row = id >> 2, ch = (id & 3) * 8;
        const float* p = src + (size_t)row * ld + ch;
        float4 f0 = *(const float4*)p;
        float4 f1 = *(const float4*)(p + 4);
        __bf16 v8[8] = {(__bf16)f0.x, (__bf16)f0.y, (__bf16)f0.z, (__bf16)f0.w,
                        (__bf16)f1.x, (__bf16)f1.y, (__bf16)f1.z, (__bf16)f1.w};
        *(uint4*)(dst + row * LDK + ch) = *(const uint4*)v8;
    }
}
template <int NI, int NJ>
__device__ __forceinline__ void mfma_tile(const __bf16* As, const __bf16* Bs,
                                          int wm, int wn, int fr, int fg,
                                          f32x4 (&acc)[NI][NJ]) {
    bf16x8 af[NI], bv[NJ];
    #pragma unroll
    for (int i = 0; i < NI; ++i)
        af[i] = *(const bf16x8*)(As + (wm + i * 16 + fr) * LDK + fg * 8);
    #pragma unroll
    for (int j = 0; j < NJ; ++j)
        bv[j] = *(const bf16x8*)(Bs + (wn + j * 16 + fr) * LDK + fg * 8);
    #pragma unroll
    for (int i = 0; i < NI; ++i)
        #pragma unroll
        for (int j = 0; j < NJ; ++j)
            acc[i][j] = mfma16(af[i], bv[j], acc[i][j]);
}

// ---------------- Q/K projection (f32 A x bf16 W^T), 128^2 tile ----------------
__global__ __launch_bounds__(256) void k_proj_gemm(
    const float* __restrict__ Af, const __bf16* __restrict__ Bt,
    const float* __restrict__ bias, float scale, __bf16* __restrict__ out) {
    __shared__ __bf16 As[128 * LDK];
    __shared__ __bf16 Bs[128 * LDK];
    int m0 = blockIdx.y * 128, n0 = blockIdx.x * 128;
    int t = threadIdx.x, lane = t & 63, w = t >> 6;
    int wm = (w >> 1) * 64, wn = (w & 1) * 64;
    int fr = lane & 15, fg = lane >> 4;
    f32x4 acc[4][4] = {};
    for (int k0 = 0; k0 < D_; k0 += 32) {
        __syncthreads();
        stage128_f32(As, Af + (size_t)m0 * D_ + k0, D_, t);
        stage128_bf16(Bs, Bt + (size_t)n0 * D_ + k0, D_, t);
        __syncthreads();
        mfma_tile<4, 4>(As, Bs, wm, wn, fr, fg, acc);
    }
    #pragma unroll
    for (int j = 0; j < 4; ++j) {
        int n = n0 + wn + j * 16 + fr;
        float bv = bias[n];
        #pragma unroll
        for (int i = 0; i < 4; ++i)
            #pragma unroll
            for (int jj = 0; jj < 4; ++jj) {
                int m = m0 + wm + i * 16 + fg * 4 + jj;
                out[(size_t)m * (H_ * A_) + n] = (__bf16)((acc[i][j][jj] + bv) * scale);
            }
    }
}

// ---------------- scores + exp + row-sum; coalesced P store via LDS ----------------
__global__ __launch_bounds__(256) void k_scores(
    const __bf16* __restrict__ qpb, const __bf16* __restrict__ kpb,
    __bf16* __restrict__ P, float* __restrict__ invl, int hg0) {
    __shared__ __bf16 Qs[64 * 72];
    __shared__ __bf16 Ks[64 * 72];
    __shared__ __bf16 Ps[64 * 72];
    int qt = blockIdx.x;
    int hl = blockIdx.y;
    int h = hg0 + hl;
    int s0 = qt * 64;
    int t = threadIdx.x, lane = t & 63, w = t >> 6;
    int fr = lane & 15, fg = lane >> 4;
    __bf16* Pb = P + (size_t)hl * S_ * S_;
    float* ilb = invl + (size_t)hl * S_;
    #pragma unroll
    for (int i = 0; i < 2; ++i) {
        int id = t + i * 256;
        int row = id >> 3, ch = (id & 7) * 8;
        *(uint4*)(Qs + row * 72 + ch) =
            *(const uint4*)(qpb + (size_t)(s0 + row) * (H_ * A_) + h * A_ + ch);
    }
    float lsum[4] = {0.f, 0.f, 0.f, 0.f};
    for (int kt = 0; kt <= qt; ++kt) {
        int t0 = kt * 64;
        __syncthreads();
        #pragma unroll
        for (int i = 0; i < 2; ++i) {
            int id = t + i * 256;
            int row = id >> 3, ch = (id & 7) * 8;
            *(uint4*)(Ks + row * 72 + ch) =
                *(const uint4*)(kpb + (size_t)(t0 + row) * (H_ * A_) + h * A_ + ch);
        }
        __syncthreads();
        f32x4 sacc[4] = {};
        #pragma unroll
        for (int st = 0; st < 2; ++st) {
            bf16x8 aq = *(const bf16x8*)(Qs + (w * 16 + fr) * 72 + st * 32 + fg * 8);
            #pragma unroll
            for (int c = 0; c < 4; ++c) {
                bf16x8 bkf = *(const bf16x8*)(Ks + (c * 16 + fr) * 72 + st * 32 + fg * 8);
                sacc[c] = mfma16(aq, bkf, sacc[c]);
            }
        }
        bool diag = (kt == qt);
        #pragma unroll
        for (int c = 0; c < 4; ++c) {
            int tg = t0 + c * 16 + fr;
            #pragma unroll
            for (int jj = 0; jj < 4; ++jj) {
                int sg = s0 + w * 16 + fg * 4 + jj;
                float p = exp2f(sacc[c][jj] * L2E);
                if (diag && tg > sg) p = 0.f;
                lsum[jj] += p;
                Ps[(w * 16 + fg * 4 + jj) * 72 + c * 16 + fr] = (__bf16)p;
            }
        }
        __syncthreads();
        #pragma unroll
        for (int i = 0; i < 2; ++i) {
            int id = t + i * 256;
            int row = id >> 3, ch = (id & 7) * 8;
            *(uint4*)(Pb + (size_t)(s0 + row) * S_ + t0 + ch) =
                *(const uint4*)(Ps + row * 72 + ch);
        }
    }
    // zero-fill past the diagonal up to the next 256 boundary (pv uses 256-row tiles)
    int ktEnd = ((qt >> 2) + 1) << 2;
    for (int kt2 = qt + 1; kt2 < ktEnd; ++kt2) {
        int t0 = kt2 * 64;
        uint4 z = {0, 0, 0, 0};
        #pragma unroll
        for (int i = 0; i < 2; ++i) {
            int id = t + i * 256;
            int row = id >> 3, ch = (id & 7) * 8;
            *(uint4*)(Pb + (size_t)(s0 + row) * S_ + t0 + ch) = z;
        }
    }
    #pragma unroll
    for (int jj = 0; jj < 4; ++jj) {
        float v = lsum[jj];
        v += __shfl_xor(v, 1);
        v += __shfl_xor(v, 2);
        v += __shfl_xor(v, 4);
        v += __shfl_xor(v, 8);
        if (fr == 0)
            ilb[s0 + w * 16 + fg * 4 + jj] = 1.f / v;
    }
}

// ---------------- P @ V, 256^2 8-phase pipelined, 1/l epilogue ----------------
__global__ __launch_bounds__(512) void k_pv(
    const __bf16* __restrict__ P, const __bf16* __restrict__ kvtb,
    const float* __restrict__ invl, __bf16* __restrict__ att, int aslot0) {
    __shared__ __bf16 L[2][4][8192];  // [buf][A0,A1,B0,B1][128x64]
    int hl = blockIdx.z, mt = blockIdx.y, n0 = blockIdx.x * 256;
    int m0 = mt * 256;
    int nt = (mt + 1) * 4;  // causal K-tiles of 64
    int t = threadIdx.x, lane = t & 63, w = t >> 6;
    int wr = w >> 2, wc = w & 3;
    int fr = lane & 15, fg = lane >> 4;
    const __bf16* Ab = P + (size_t)hl * S_ * S_ + (size_t)m0 * S_;
    const __bf16* Bb = kvtb + (size_t)n0 * S_;
    f32x4 acc[8][4] = {};
    auto stg = [&](int tt, int h, int buf) {
        const __bf16* s = (h < 2) ? (Ab + (size_t)(h * 128) * S_ + tt * 64)
                                  : (Bb + (size_t)((h - 2) * 128) * S_ + tt * 64);
        stage_half(s, S_, &L[buf][h][0], w, lane);
    };
    auto loads = [&](const __bf16* Ah, const __bf16* Bh, int rb0, int mh, int nh,
                     bf16x8 (&af)[4][2], bf16x8 (&bv)[2][2]) {
        #pragma unroll
        for (int i = 0; i < 4; ++i)
            #pragma unroll
            for (int ks = 0; ks < 2; ++ks)
                af[i][ks] = fragS(Ah, mh * 64 + i * 16 + fr, ks, fg);
        #pragma unroll
        for (int j = 0; j < 2; ++j)
            #pragma unroll
            for (int ks = 0; ks < 2; ++ks)
                bv[j][ks] = fragS(Bh, rb0 + nh * 32 + j * 16 + fr, ks, fg);
    };
    stg(0, 0, 0); stg(0, 1, 0); stg(0, 2, 0); stg(0, 3, 0);
    int cur = 0;
    for (int tt = 0; tt < nt; ++tt) {
        bool pre = (tt + 1 < nt);
        const __bf16* Ah = &L[cur][wr][0];
        const __bf16* Bh = &L[cur][2 + (wc >> 1)][0];
        int rb0 = (wc & 1) * 64;
        #pragma unroll
        for (int ph = 0; ph < 4; ++ph) {
            const int mh = ph >> 1, nh = ph & 1;
            bf16x8 af[4][2], bv[2][2];
            if (ph == 0) {
                if (pre) {
                    stg(tt + 1, 0, cur ^ 1);
                    asm volatile("s_waitcnt vmcnt(2)" ::: "memory");
                } else {
                    asm volatile("s_waitcnt vmcnt(0)" ::: "memory");
                }
                __builtin_amdgcn_s_barrier();
                __builtin_amdgcn_sched_barrier(0);
                loads(Ah, Bh, rb0, mh, nh, af, bv);
            } else {
                loads(Ah, Bh, rb0, mh, nh, af, bv);
                if (pre) stg(tt + 1, ph, cur ^ 1);
                __builtin_amdgcn_s_barrier();
                __builtin_amdgcn_sched_barrier(0);
            }
            __builtin_amdgcn_s_setprio(1);
            #pragma unroll
            for (int i = 0; i < 4; ++i)
                #pragma unroll
                for (int j = 0; j < 2; ++j) {
                    acc[mh * 4 + i][nh * 2 + j] =
                        mfma16(af[i][0], bv[j][0], acc[mh * 4 + i][nh * 2 + j]);
                    acc[mh * 4 + i][nh * 2 + j] =
                        mfma16(af[i][1], bv[j][1], acc[mh * 4 + i][nh * 2 + j]);
                }
            __builtin_amdgcn_s_setprio(0);
            __builtin_amdgcn_sched_barrier(0);
            __builtin_amdgcn_s_barrier();
        }
        cur ^= 1;
    }
    const float* ilb = invl + (size_t)hl * S_;
    __bf16* ob = att + (size_t)(aslot0 + hl) * S_ * D_;
    #pragma unroll
    for (int mi = 0; mi < 8; ++mi)
        #pragma unroll
        for (int jj = 0; jj < 4; ++jj) {
            int m = m0 + wr * 128 + mi * 16 + fg * 4 + jj;
            float il = ilb[m];
            #pragma unroll
            for (int nj = 0; nj < 4; ++nj) {
                int n = n0 + wc * 64 + nj * 16 + fr;
                ob[(size_t)m * D_ + n] = (__bf16)(acc[mi][nj][jj] * il);
            }
        }
}

// ---------------- per-head Wo GEMM + bias + relu partials, 256^2 8-phase ----------------
__global__ __launch_bounds__(512) void k_headsum(
    const __bf16* __restrict__ att, const __bf16* __restrict__ Wot,
    const float* __restrict__ bo, float* __restrict__ asum,
    int hb0, int accum) {
    __shared__ __bf16 L[2][4][8192];
    int p = blockIdx.z;  // head within window (HC=1)
    int mt = blockIdx.y, n0 = blockIdx.x * 256;
    int m0 = mt * 256;
    int habs = hb0 + p;
    int t = threadIdx.x, lane = t & 63, w = t >> 6;
    int wr = w >> 2, wc = w & 3;
    int fr = lane & 15, fg = lane >> 4;
    const __bf16* Ab = att + ((size_t)p * S_ + m0) * D_;
    const __bf16* Bb = Wot + ((size_t)habs * D_ + n0) * D_;
    float bv4[4];
    #pragma unroll
    for (int j = 0; j < 4; ++j)
        bv4[j] = bo[(size_t)habs * D_ + n0 + wc * 64 + j * 16 + fr];
    f32x4 acc[8][4] = {};
    auto stg = [&](int tt, int h, int buf) {
        const __bf16* s = (h < 2) ? (Ab + (size_t)(h * 128) * D_ + tt * 64)
                                  : (Bb + (size_t)((h - 2) * 128) * D_ + tt * 64);
        stage_half(s, D_, &L[buf][h][0], w, lane);
    };
    auto loads = [&](const __bf16* Ah, const __bf16* Bh, int rb0, int mh, int nh,
                     bf16x8 (&af)[4][2], bf16x8 (&bv)[2][2]) {
        #pragma unroll
        for (int i = 0; i < 4; ++i)
            #pragma unroll
            for (int ks = 0; ks < 2; ++ks)
                af[i][ks] = fragS(Ah, mh * 64 + i * 16 + fr, ks, fg);
        #pragma unroll
        for (int j = 0; j < 2; ++j)
            #pragma unroll
            for (int ks = 0; ks < 2; ++ks)
                bv[j][ks] = fragS(Bh, rb0 + nh * 32 + j * 16 + fr, ks, fg);
    };
    stg(0, 0, 0); stg(0, 1, 0); stg(0, 2, 0); stg(0, 3, 0);
    int cur = 0;
    const int nt = D_ / 64;  // 16
    for (int tt = 0; tt < nt; ++tt) {
        bool pre = (tt + 1 < nt);
        const __bf16* Ah = &L[cur][wr][0];
        const __bf16* Bh = &L[cur][2 + (wc >> 1)][0];
        int rb0 = (wc & 1) * 64;
        #pragma unroll
        for (int ph = 0; ph < 4; ++ph) {
            const int mh = ph >> 1, nh = ph & 1;
            bf16x8 af[4][2], bv[2][2];
            if (ph == 0) {
                if (pre) {
                    stg(tt + 1, 0, cur ^ 1);
                    asm volatile("s_waitcnt vmcnt(2)" ::: "memory");
                } else {
                    asm volatile("s_waitcnt vmcnt(0)" ::: "memory");
                }
                __builtin_amdgcn_s_barrier();
                __builtin_amdgcn_sched_barrier(0);
                loads(Ah, Bh, rb0, mh, nh, af, bv);
            } else {
                loads(Ah, Bh, rb0, mh, nh, af, bv);
                if (pre) stg(tt + 1, ph, cur ^ 1);
                __builtin_amdgcn_s_barrier();
                __builtin_amdgcn_sched_barrier(0);
            }
            __builtin_amdgcn_s_setprio(1);
            #pragma unroll
            for (int i = 0; i < 4; ++i)
                #pragma unroll
                for (int j = 0; j < 2; ++j) {
                    acc[mh * 4 + i][nh * 2 + j] =
                        mfma16(af[i][0], bv[j][0], acc[mh * 4 + i][nh * 2 + j]);
                    acc[mh * 4 + i][nh * 2 + j] =
                        mfma16(af[i][1], bv[j][1], acc[mh * 4 + i][nh * 2 + j]);
                }
            __builtin_amdgcn_s_setprio(0);
            __builtin_amdgcn_sched_barrier(0);
            __builtin_amdgcn_s_barrier();
        }
        cur ^= 1;
    }
    float* dst = asum + ((size_t)p * S_ + m0) * D_;
    #pragma unroll
    for (int mi = 0; mi < 8; ++mi)
        #pragma unroll
        for (int jj = 0; jj < 4; ++jj) {
            int mr = wr * 128 + mi * 16 + fg * 4 + jj;
            #pragma unroll
            for (int nj = 0; nj < 4; ++nj) {
                int nc = n0 + wc * 64 + nj * 16 + fr;
                float v = fmaxf(acc[mi][nj][jj] + bv4[nj], 0.f);
                if (accum)
                    dst[(size_t)mr * D_ + nc] += v;
                else
                    dst[(size_t)mr * D_ + nc] = v;
            }
        }
}

// ---------------- residual + NPL-partial-sum + LayerNorm (per batch) ----------------
__global__ __launch_bounds__(256) void k_ln(
    const float* __restrict__ x1b, const float* __restrict__ parts,
    const float* __restrict__ gamma, const float* __restrict__ beta,
    float* __restrict__ outb, int NPL) {
    int row = blockIdx.x;
    size_t base = (size_t)row * D_;
    int c = threadIdx.x * 4;
    float4 a = *(const float4*)(x1b + base + c);
    float x[4] = {a.x, a.y, a.z, a.w};
    for (int p = 0; p < NPL; ++p) {
        const float4 v = *(const float4*)(parts + ((size_t)p * S_ + row) * D_ + c);
        x[0] += v.x; x[1] += v.y; x[2] += v.z; x[3] += v.w;
    }
    float sm = x[0] + x[1] + x[2] + x[3];
    float s2 = x[0] * x[0] + x[1] * x[1] + x[2] * x[2] + x[3] * x[3];
    #pragma unroll
    for (int m = 32; m >= 1; m >>= 1) {
        sm += __shfl_xor(sm, m);
        s2 += __shfl_xor(s2, m);
    }
    __shared__ float r1[4], r2[4];
    int w = threadIdx.x >> 6;
    if ((threadIdx.x & 63) == 0) { r1[w] = sm; r2[w] = s2; }
    __syncthreads();
    sm = r1[0] + r1[1] + r1[2] + r1[3];
    s2 = r2[0] + r2[1] + r2[2] + r2[3];
    float mean = sm * (1.f / D_);
    float var = s2 * (1.f / D_) - mean * mean;
    float rstd = rsqrtf(var + LN_EPS);
    #pragma unroll
    for (int jj = 0; jj < 4; ++jj)
        outb[base + c + jj] = gamma[c + jj] * (x[jj] - mean) * rstd + beta[c + jj];
}

// ---------------- host ----------------
extern "C" void kernel_launch(void* const* d_in, const int* in_sizes, int n_in,
                              void* d_out, int out_size, void* d_ws, size_t ws_size,
                              hipStream_t stream) {
    (void)in_sizes; (void)n_in; (void)out_size;
    const float* qin   = (const float*)d_in[0];
    const float* kvin  = (const float*)d_in[1];
    const float* Wq    = (const float*)d_in[2];
    const float* bq    = (const float*)d_in[3];
    const float* Wk    = (const float*)d_in[4];
    const float* bk    = (const float*)d_in[5];
    const float* Wo    = (const float*)d_in[6];
    const float* bo    = (const float*)d_in[7];
    const float* gamma = (const float*)d_in[8];
    const float* beta  = (const float*)d_in[9];
    float* out = (float*)d_out;
    char* ws = (char*)d_ws;

    size_t off = 0;
    auto alloc = [&](size_t bytes) {
        size_t o = off;
        off += (bytes + 255) & ~(size_t)255;
        return o;
    };
    size_t o_wqt = alloc((size_t)H_ * A_ * D_ * 2);
    size_t o_wkt = alloc((size_t)H_ * A_ * D_ * 2);
    size_t o_wot = alloc((size_t)H_ * D_ * D_ * 2);
    size_t o_kvt = alloc((size_t)B_ * D_ * S_ * 2);
    size_t o_qp  = alloc((size_t)B_ * S_ * H_ * A_ * 2);
    size_t o_kp  = alloc((size_t)B_ * S_ * H_ * A_ * 2);
    size_t fixed = off;

    // AG = heads per headsum window (1 head per block, AG partials);
    // HGp = heads per scores/pv dispatch. P aliases asum only when AG==16
    // (single window per batch -> disjoint lifetimes).
    int AG = 1, HGp = 1;
    {
        const int ags[6] = {16, 8, 8, 4, 2, 1};
        const int hgs[6] = {8, 8, 4, 4, 2, 1};
        for (int i = 0; i < 6; ++i) {
            int ag = ags[i], hg = hgs[i];
            size_t pB = (size_t)hg * S_ * S_ * 2;
            size_t aB = (size_t)ag * S_ * D_ * 4;
            size_t un = (ag == 16) ? (pB > aB ? pB : aB) : pB + aB;
            size_t need = fixed + (size_t)ag * S_ * D_ * 2 + un
                        + (size_t)hg * S_ * 4 + (1u << 16);
            if (need <= ws_size) { AG = ag; HGp = hg; break; }
        }
    }
    size_t o_att = alloc((size_t)AG * S_ * D_ * 2);
    size_t o_P, o_as;
    if (AG == 16) {
        size_t pB = (size_t)HGp * S_ * S_ * 2;
        size_t aB = (size_t)AG * S_ * D_ * 4;
        size_t o_un = alloc(pB > aB ? pB : aB);
        o_P = o_un; o_as = o_un;
    } else {
        o_P  = alloc((size_t)HGp * S_ * S_ * 2);
        o_as = alloc((size_t)AG * S_ * D_ * 4);
    }
    size_t o_il = alloc((size_t)HGp * S_ * 4);

    __bf16* wqt = (__bf16*)(ws + o_wqt);
    __bf16* wkt = (__bf16*)(ws + o_wkt);
    __bf16* wot = (__bf16*)(ws + o_wot);
    __bf16* kvt = (__bf16*)(ws + o_kvt);
    __bf16* qp  = (__bf16*)(ws + o_qp);
    __bf16* kp  = (__bf16*)(ws + o_kp);
    __bf16* att = (__bf16*)(ws + o_att);
    __bf16* Pp  = (__bf16*)(ws + o_P);
    float*  asum = (float*)(ws + o_as);
    float*  il  = (float*)(ws + o_il);

    // transposed bf16 weights + V^T
    k_tr_cvt<<<dim3(A_ / 32, D_ / 32, H_), dim3(32, 8), 0, stream>>>(Wq, wqt, D_, A_);
    k_tr_cvt<<<dim3(A_ / 32, D_ / 32, H_), dim3(32, 8), 0, stream>>>(Wk, wkt, D_, A_);
    k_tr_cvt<<<dim3(D_ / 32, D_ / 32, H_), dim3(32, 8), 0, stream>>>(Wo, wot, D_, D_);
    k_tr_cvt<<<dim3(D_ / 32, S_ / 32, B_), dim3(32, 8), 0, stream>>>(kvin, kvt, S_, D_);
    // projections (q pre-scaled by 1/sqrt(A))
    k_proj_gemm<<<dim3(8, 64), 256, 0, stream>>>(qin, wqt, bq, 0.125f, qp);
    k_proj_gemm<<<dim3(8, 64), 256, 0, stream>>>(kvin, wkt, bk, 1.0f, kp);

    for (int b = 0; b < B_; ++b) {
        const __bf16* qpb  = qp + (size_t)b * S_ * (H_ * A_);
        const __bf16* kpb  = kp + (size_t)b * S_ * (H_ * A_);
        const __bf16* kvtb = kvt + (size_t)b * D_ * S_;
        for (int hb0 = 0; hb0 < H_; hb0 += AG) {
            for (int hg0 = hb0; hg0 < hb0 + AG; hg0 += HGp) {
                k_scores<<<dim3(32, HGp), 256, 0, stream>>>(qpb, kpb, Pp, il, hg0);
                k_pv<<<dim3(D_ / 256, S_ / 256, HGp), 512, 0, stream>>>(
                    Pp, kvtb, il, att, hg0 - hb0);
            }
            k_headsum<<<dim3(D_ / 256, S_ / 256, AG), 512, 0, stream>>>(
                att, wot, bo, asum, hb0, hb0 != 0);
        }
        k_ln<<<S_, 256, 0, stream>>>(qin + (size_t)b * S_ * D_, asum, gamma, beta,
                                     out + (size_t)b * S_ * D_, AG);
    }
}